// Round 1
// baseline (486.768 us; speedup 1.0000x reference)
//
#include <hip/hip_runtime.h>
#include <hip/hip_bf16.h>

#define N_TOK 8192
#define DIM   2048
#define NEXP  8
#define BM    128
#define BN    128
#define BK    64
#define MAXT  71   // max row tiles: 8192/128 + (E-1)

typedef __attribute__((ext_vector_type(8))) short  short8;
typedef __attribute__((ext_vector_type(4))) float  f32x4;
typedef __attribute__((ext_vector_type(4))) unsigned int u32x4;

static __device__ __forceinline__ unsigned int pack_bf2(float a, float b) {
  union { __hip_bfloat16 h; unsigned short u; } ca, cb;
  ca.h = __float2bfloat16(a);
  cb.h = __float2bfloat16(b);
  return ((unsigned int)cb.u << 16) | (unsigned int)ca.u;
}

// ---------------- init: zero counters, write loss=0 ----------------
__global__ void init_kernel(int* __restrict__ scratch, float* __restrict__ out) {
  int t = threadIdx.x;
  if (t < 48) scratch[t] = 0;          // counts[0..7]@0, fill@16, base@32
  if (t == 63) out[(size_t)N_TOK * DIM] = 0.0f;   // loss output
}

// ---------------- router: one wave per token, fp64 logits ----------------
__global__ __launch_bounds__(256) void router_kernel(
    const float* __restrict__ x, const float* __restrict__ rw,
    const float* __restrict__ rb, int* __restrict__ eid,
    float* __restrict__ gate, int* __restrict__ counts)
{
  int tok  = (int)((blockIdx.x * 256 + threadIdx.x) >> 6);
  int lane = threadIdx.x & 63;
  const float* xr = x + (size_t)tok * DIM;
  double s[NEXP];
#pragma unroll
  for (int e = 0; e < NEXP; e++) s[e] = 0.0;
  for (int d = lane; d < DIM; d += 64) {
    float xv = xr[d];
#pragma unroll
    for (int e = 0; e < NEXP; e++)
      s[e] += (double)xv * (double)rw[e * DIM + d];
  }
#pragma unroll
  for (int e = 0; e < NEXP; e++) {
    double v = s[e];
#pragma unroll
    for (int off = 32; off > 0; off >>= 1) v += __shfl_xor(v, off, 64);
    s[e] = v;
  }
  if (lane == 0) {
    double lg[NEXP];
    double lmax = -1e300; int best = 0;
#pragma unroll
    for (int e = 0; e < NEXP; e++) {
      lg[e] = s[e] + (double)rb[e];
      if (lg[e] > lmax) { lmax = lg[e]; best = e; }  // strict > == first-occurrence argmax
    }
    float den = 0.f;
#pragma unroll
    for (int e = 0; e < NEXP; e++) den += expf((float)(lg[e] - lmax));
    eid[tok]  = best;
    gate[tok] = 1.0f / den;            // top softmax prob
    atomicAdd(&counts[best], 1);
  }
}

// ---------------- scan: expert bases + padded tile table ----------------
__global__ void scan_kernel(const int* __restrict__ counts, int* __restrict__ basep,
                            int* __restrict__ tileE, int* __restrict__ tileRB,
                            int* __restrict__ tileRows, int* __restrict__ ntiles)
{
  if (threadIdx.x != 0) return;
  int b = 0, nt = 0;
  for (int e = 0; e < NEXP; e++) {
    basep[e] = b;
    int c = counts[e];
    for (int t = 0; t < c; t += BM) {
      tileE[nt]    = e;
      tileRB[nt]   = b + t;
      tileRows[nt] = (c - t) < BM ? (c - t) : BM;
      nt++;
    }
    b += c;
  }
  *ntiles = nt;
}

// ---------------- permute: group tokens by expert ----------------
__global__ void permute_kernel(const int* __restrict__ eid, const int* __restrict__ basep,
                               int* __restrict__ fill, int* __restrict__ perm)
{
  int i = blockIdx.x * blockDim.x + threadIdx.x;
  if (i >= N_TOK) return;
  int e = eid[i];
  int pos = basep[e] + atomicAdd(&fill[e], 1);
  perm[pos] = i;
}

// ---------------- grouped GEMM: out[tok] = (x[tok] @ W[e]^T + b[e]) * gate ----------------
__global__ __launch_bounds__(256) void moe_gemm(
    const float* __restrict__ x, const float* __restrict__ ew,
    const float* __restrict__ eb, const float* __restrict__ gate,
    const int* __restrict__ perm, const int* __restrict__ tileE,
    const int* __restrict__ tileRB, const int* __restrict__ tileRows,
    const int* __restrict__ ntiles, float* __restrict__ out)
{
  int rt = blockIdx.x;
  if (rt >= *ntiles) return;
  const int e       = tileE[rt];
  const int rowbase = tileRB[rt];
  const int nrows   = tileRows[rt];
  const int col0    = blockIdx.y * BN;

  __shared__ unsigned short As[BM][BK];   // XOR-swizzled rows (128B each)
  __shared__ unsigned short Bs[BN][BK];
  __shared__ int   aRowS[BM];
  __shared__ float gateS[BM];

  const int tid = threadIdx.x;
  if (tid < BM) {
    int p = rowbase + tid;
    int tok = perm[p < (N_TOK - 1) ? p : (N_TOK - 1)];
    aRowS[tid] = tok;
    gateS[tid] = gate[tok];
  }
  __syncthreads();

  const float* wBase = ew + (size_t)e * DIM * DIM;
  const int lane = tid & 63;
  const int wid  = tid >> 6;
  const int wm   = (wid >> 1) * 64;
  const int wn   = (wid & 1) * 64;

  f32x4 acc[4][4] = {};

  char* AsB = (char*)&As[0][0];
  char* BsB = (char*)&Bs[0][0];

  for (int kt = 0; kt < DIM; kt += BK) {
    // ---- stage A (gathered rows) and B (expert weight rows), fp32 -> bf16 ----
#pragma unroll
    for (int i = 0; i < 4; i++) {
      int c   = tid + 256 * i;
      int row = c >> 3;
      int kc  = c & 7;
      {
        const float* src = x + (size_t)aRowS[row] * DIM + kt + kc * 8;
        float4 f0 = *reinterpret_cast<const float4*>(src);
        float4 f1 = *reinterpret_cast<const float4*>(src + 4);
        u32x4 pk;
        pk[0] = pack_bf2(f0.x, f0.y); pk[1] = pack_bf2(f0.z, f0.w);
        pk[2] = pack_bf2(f1.x, f1.y); pk[3] = pack_bf2(f1.z, f1.w);
        int off = row * (BK * 2) + ((kc * 16) ^ ((row & 7) << 4));
        *reinterpret_cast<u32x4*>(AsB + off) = pk;
      }
      {
        const float* src = wBase + (size_t)(col0 + row) * DIM + kt + kc * 8;
        float4 f0 = *reinterpret_cast<const float4*>(src);
        float4 f1 = *reinterpret_cast<const float4*>(src + 4);
        u32x4 pk;
        pk[0] = pack_bf2(f0.x, f0.y); pk[1] = pack_bf2(f0.z, f0.w);
        pk[2] = pack_bf2(f1.x, f1.y); pk[3] = pack_bf2(f1.z, f1.w);
        int off = row * (BK * 2) + ((kc * 16) ^ ((row & 7) << 4));
        *reinterpret_cast<u32x4*>(BsB + off) = pk;
      }
    }
    __syncthreads();

    // ---- MFMA on the 64-wide K slab (2 x K=32) ----
#pragma unroll
    for (int kk = 0; kk < 2; kk++) {
      int kbyte = kk * 64 + ((lane >> 4) * 16);
      short8 af[4], bfr[4];
#pragma unroll
      for (int m = 0; m < 4; m++) {
        int row = wm + m * 16 + (lane & 15);
        int off = row * (BK * 2) + (kbyte ^ ((row & 7) << 4));
        af[m] = *reinterpret_cast<const short8*>(AsB + off);
      }
#pragma unroll
      for (int n = 0; n < 4; n++) {
        int row = wn + n * 16 + (lane & 15);
        int off = row * (BK * 2) + (kbyte ^ ((row & 7) << 4));
        bfr[n] = *reinterpret_cast<const short8*>(BsB + off);
      }
#pragma unroll
      for (int m = 0; m < 4; m++)
#pragma unroll
        for (int n = 0; n < 4; n++)
          acc[m][n] = __builtin_amdgcn_mfma_f32_16x16x32_bf16(af[m], bfr[n], acc[m][n], 0, 0, 0);
    }
    __syncthreads();
  }

  // ---- epilogue: +bias, *gate, scatter by token ----
  const int cbase = col0 + wn;
  float bias[4];
#pragma unroll
  for (int n = 0; n < 4; n++)
    bias[n] = eb[(size_t)e * DIM + cbase + n * 16 + (lane & 15)];

#pragma unroll
  for (int m = 0; m < 4; m++) {
#pragma unroll
    for (int rg = 0; rg < 4; rg++) {
      int r = wm + m * 16 + ((lane >> 4) << 2) + rg;
      if (r < nrows) {
        int tok = aRowS[r];
        float g = gateS[r];
        float* orow = out + (size_t)tok * DIM + cbase;
#pragma unroll
        for (int n = 0; n < 4; n++)
          orow[n * 16 + (lane & 15)] = (acc[m][n][rg] + bias[n]) * g;
      }
    }
  }
}

extern "C" void kernel_launch(void* const* d_in, const int* in_sizes, int n_in,
                              void* d_out, int out_size, void* d_ws, size_t ws_size,
                              hipStream_t stream)
{
  const float* x  = (const float*)d_in[0];
  const float* ew = (const float*)d_in[1];
  const float* eb = (const float*)d_in[2];
  const float* rw = (const float*)d_in[3];
  const float* rb = (const float*)d_in[4];
  float* out = (float*)d_out;

  char* ws = (char*)d_ws;
  int*   eid      = (int*)(ws);                 // 8192 ints
  float* gate     = (float*)(ws + 32 * 1024);   // 8192 floats
  int*   counts   = (int*)(ws + 64 * 1024);     // [0..7]
  int*   fill     = counts + 16;
  int*   basep    = counts + 32;
  int*   tileE    = counts + 48;                // 128 slots
  int*   tileRB   = tileE + 128;
  int*   tileRows = tileE + 256;
  int*   ntiles   = tileE + 384;
  int*   perm     = tileE + 512;                // 8192 ints

  init_kernel<<<1, 64, 0, stream>>>(counts, out);
  router_kernel<<<N_TOK / 4, 256, 0, stream>>>(x, rw, rb, eid, gate, counts);
  scan_kernel<<<1, 64, 0, stream>>>(counts, basep, tileE, tileRB, tileRows, ntiles);
  permute_kernel<<<N_TOK / 256, 256, 0, stream>>>(eid, basep, fill, perm);
  dim3 grid(MAXT, DIM / BN);
  moe_gemm<<<grid, 256, 0, stream>>>(x, ew, eb, gate, perm, tileE, tileRB, tileRows, ntiles, out);
}

// Round 2
// 378.871 us; speedup vs baseline: 1.2848x; 1.2848x over previous
//
#include <hip/hip_runtime.h>
#include <hip/hip_bf16.h>

#define N_TOK 8192
#define DIM   2048
#define NEXP  8
#define BM    128
#define BN    128
#define BK    64
#define MAXT  71   // max row tiles: 8192/128 + (E-1)

typedef __attribute__((ext_vector_type(8))) short  short8;
typedef __attribute__((ext_vector_type(4))) float  f32x4;
typedef __attribute__((ext_vector_type(4))) unsigned int u32x4;

static __device__ __forceinline__ unsigned int pack_bf2(float a, float b) {
  union { __hip_bfloat16 h; unsigned short u; } ca, cb;
  ca.h = __float2bfloat16(a);
  cb.h = __float2bfloat16(b);
  return ((unsigned int)cb.u << 16) | (unsigned int)ca.u;
}

static __device__ __forceinline__ void gload16(const unsigned short* g, void* l) {
  __builtin_amdgcn_global_load_lds(
      (const __attribute__((address_space(1))) unsigned int*)(const void*)g,
      (__attribute__((address_space(3))) unsigned int*)l, 16, 0, 0);
}

// ---------------- init: zero counters, write loss=0 ----------------
__global__ void init_kernel(int* __restrict__ scratch, float* __restrict__ out) {
  int t = threadIdx.x;
  if (t < 48) scratch[t] = 0;          // counts[0..7]@0, fill@16, base@32
  if (t == 63) out[(size_t)N_TOK * DIM] = 0.0f;   // loss output
}

// ---------------- router (+ fused x -> bf16 convert) ----------------
__global__ __launch_bounds__(256) void router_kernel(
    const float* __restrict__ x, const float* __restrict__ rw,
    const float* __restrict__ rb, int* __restrict__ eid,
    float* __restrict__ gate, int* __restrict__ counts,
    unsigned short* __restrict__ xb)
{
  int tok  = (int)((blockIdx.x * 256 + threadIdx.x) >> 6);
  int lane = threadIdx.x & 63;
  const float4* xr = reinterpret_cast<const float4*>(x + (size_t)tok * DIM);
  double s[NEXP];
#pragma unroll
  for (int e = 0; e < NEXP; e++) s[e] = 0.0;
#pragma unroll
  for (int it = 0; it < DIM / 256; it++) {
    int v = lane + it * 64;            // float4 index within row
    float4 xv = xr[v];
    if (xb) {
      uint2 pk = make_uint2(pack_bf2(xv.x, xv.y), pack_bf2(xv.z, xv.w));
      *reinterpret_cast<uint2*>(xb + (size_t)tok * DIM + v * 4) = pk;
    }
#pragma unroll
    for (int e = 0; e < NEXP; e++) {
      float4 wv = reinterpret_cast<const float4*>(rw + (size_t)e * DIM)[v];
      s[e] = fma((double)xv.x, (double)wv.x, s[e]);
      s[e] = fma((double)xv.y, (double)wv.y, s[e]);
      s[e] = fma((double)xv.z, (double)wv.z, s[e]);
      s[e] = fma((double)xv.w, (double)wv.w, s[e]);
    }
  }
#pragma unroll
  for (int e = 0; e < NEXP; e++) {
    double v = s[e];
#pragma unroll
    for (int off = 32; off > 0; off >>= 1) v += __shfl_xor(v, off, 64);
    s[e] = v;
  }
  if (lane == 0) {
    double lg[NEXP];
    double lmax = -1e300; int best = 0;
#pragma unroll
    for (int e = 0; e < NEXP; e++) {
      lg[e] = s[e] + (double)rb[e];
      if (lg[e] > lmax) { lmax = lg[e]; best = e; }  // strict > == first-occurrence argmax
    }
    float den = 0.f;
#pragma unroll
    for (int e = 0; e < NEXP; e++) den += expf((float)(lg[e] - lmax));
    eid[tok]  = best;
    gate[tok] = 1.0f / den;            // top softmax prob
    atomicAdd(&counts[best], 1);
  }
}

// ---------------- W -> bf16 convert ----------------
__global__ __launch_bounds__(256) void convw_kernel(
    const float* __restrict__ w, unsigned short* __restrict__ wb)
{
  size_t idx    = (size_t)blockIdx.x * 256 + threadIdx.x;   // chunk of 8 elems
  size_t stride = (size_t)gridDim.x * 256;
  const size_t total = (size_t)NEXP * DIM * DIM / 8;
  for (; idx < total; idx += stride) {
    const float4* s = reinterpret_cast<const float4*>(w + idx * 8);
    float4 f0 = s[0], f1 = s[1];
    u32x4 pk;
    pk[0] = pack_bf2(f0.x, f0.y); pk[1] = pack_bf2(f0.z, f0.w);
    pk[2] = pack_bf2(f1.x, f1.y); pk[3] = pack_bf2(f1.z, f1.w);
    *reinterpret_cast<u32x4*>(wb + idx * 8) = pk;
  }
}

// ---------------- scan: expert bases + padded tile table ----------------
__global__ void scan_kernel(const int* __restrict__ counts, int* __restrict__ basep,
                            int* __restrict__ tileE, int* __restrict__ tileRB,
                            int* __restrict__ tileRows, int* __restrict__ ntiles)
{
  if (threadIdx.x != 0) return;
  int b = 0, nt = 0;
  for (int e = 0; e < NEXP; e++) {
    basep[e] = b;
    int c = counts[e];
    for (int t = 0; t < c; t += BM) {
      tileE[nt]    = e;
      tileRB[nt]   = b + t;
      tileRows[nt] = (c - t) < BM ? (c - t) : BM;
      nt++;
    }
    b += c;
  }
  *ntiles = nt;
}

// ---------------- permute: group tokens by expert ----------------
__global__ void permute_kernel(const int* __restrict__ eid, const int* __restrict__ basep,
                               int* __restrict__ fill, int* __restrict__ perm)
{
  int i = blockIdx.x * blockDim.x + threadIdx.x;
  if (i >= N_TOK) return;
  int e = eid[i];
  int pos = basep[e] + atomicAdd(&fill[e], 1);
  perm[pos] = i;
}

// ---------------- grouped GEMM (bf16, global_load_lds, m97 structure) ----------------
// out[tok] = (x[tok] @ W[e]^T + b[e]) * gate[tok]
__global__ __launch_bounds__(256) void moe_gemm(
    const unsigned short* __restrict__ xb, const unsigned short* __restrict__ wb,
    const float* __restrict__ eb, const float* __restrict__ gate,
    const int* __restrict__ perm, const int* __restrict__ tileE,
    const int* __restrict__ tileRB, const int* __restrict__ tileRows,
    const int* __restrict__ ntiles, float* __restrict__ out)
{
  int rt = blockIdx.x;
  if (rt >= *ntiles) return;
  const int e       = tileE[rt];
  const int rowbase = tileRB[rt];
  const int nrows   = tileRows[rt];
  const int col0    = blockIdx.y * BN;

  __shared__ unsigned short As[BM][BK];   // linear dest (global_load_lds), source pre-swizzled
  __shared__ unsigned short Bs[BN][BK];
  __shared__ int   aRowS[BM];
  __shared__ float gateS[BM];

  const int tid  = threadIdx.x;
  const int lane = tid & 63;
  const int wid  = tid >> 6;

  if (tid < BM) {
    int p = rowbase + tid;
    int tok = perm[p < (N_TOK - 1) ? p : (N_TOK - 1)];
    aRowS[tid] = tok;
    gateS[tid] = gate[tok];
  }
  __syncthreads();

  // per-lane staging sources: row = wid*32 + i*8 + (lane>>3); 16B block = (lane&7) ^ (row&7)
  // row&7 == lane>>3, so cblk = (lane&7) ^ (lane>>3)  (XOR involution, rule #21)
  const int lrow = lane >> 3;
  const int cblk = (lane & 7) ^ lrow;
  const unsigned short* wBase = wb + (size_t)e * DIM * DIM;
  const unsigned short* aSrc[4];
  const unsigned short* bSrc[4];
  char* aD[4];
  char* bD[4];
#pragma unroll
  for (int i = 0; i < 4; i++) {
    int row = wid * 32 + i * 8 + lrow;
    aSrc[i] = xb + (size_t)aRowS[row] * DIM + cblk * 8;
    bSrc[i] = wBase + (size_t)(col0 + row) * DIM + cblk * 8;
    aD[i] = (char*)&As[0][0] + (wid * 4 + i) * 1024;   // wave-uniform LDS base
    bD[i] = (char*)&Bs[0][0] + (wid * 4 + i) * 1024;
  }

  const int wm = (wid >> 1) * 64;
  const int wn = (wid & 1) * 64;
  f32x4 acc[4][4] = {};
  char* AsB = (char*)&As[0][0];
  char* BsB = (char*)&Bs[0][0];

  for (int kt = 0; kt < DIM; kt += BK) {
    // ---- stage A+B tiles direct to LDS (8 x global_load_lds dwordx4 / thread) ----
#pragma unroll
    for (int i = 0; i < 4; i++) {
      gload16(aSrc[i], aD[i]);
      gload16(bSrc[i], bD[i]);
      aSrc[i] += BK;
      bSrc[i] += BK;
    }
    __syncthreads();   // compiler emits vmcnt(0) drain -> tile visible

    // ---- MFMA on the 64-wide K slab (2 x K=32) ----
#pragma unroll
    for (int kk = 0; kk < 2; kk++) {
      int kbyte = kk * 64 + ((lane >> 4) * 16);
      short8 af[4], bfr[4];
#pragma unroll
      for (int m = 0; m < 4; m++) {
        int row = wm + m * 16 + (lane & 15);
        int off = row * (BK * 2) + (kbyte ^ ((row & 7) << 4));
        af[m] = *reinterpret_cast<const short8*>(AsB + off);
      }
#pragma unroll
      for (int n = 0; n < 4; n++) {
        int row = wn + n * 16 + (lane & 15);
        int off = row * (BK * 2) + (kbyte ^ ((row & 7) << 4));
        bfr[n] = *reinterpret_cast<const short8*>(BsB + off);
      }
#pragma unroll
      for (int m = 0; m < 4; m++)
#pragma unroll
        for (int n = 0; n < 4; n++)
          acc[m][n] = __builtin_amdgcn_mfma_f32_16x16x32_bf16(af[m], bfr[n], acc[m][n], 0, 0, 0);
    }
    __syncthreads();
  }

  // ---- epilogue: +bias, *gate, scatter by token ----
  const int cbase = col0 + wn;
  float bias[4];
#pragma unroll
  for (int n = 0; n < 4; n++)
    bias[n] = eb[(size_t)e * DIM + cbase + n * 16 + (lane & 15)];

#pragma unroll
  for (int m = 0; m < 4; m++) {
#pragma unroll
    for (int rg = 0; rg < 4; rg++) {
      int r = wm + m * 16 + ((lane >> 4) << 2) + rg;
      if (r < nrows) {
        int tok = aRowS[r];
        float g = gateS[r];
        float* orow = out + (size_t)tok * DIM + cbase;
#pragma unroll
        for (int n = 0; n < 4; n++)
          orow[n * 16 + (lane & 15)] = (acc[m][n][rg] + bias[n]) * g;
      }
    }
  }
}

// ---------------- fallback grouped GEMM (round-1, fp32 source, inline cvt) ----------------
__global__ __launch_bounds__(256) void moe_gemm_fb(
    const float* __restrict__ x, const float* __restrict__ ew,
    const float* __restrict__ eb, const float* __restrict__ gate,
    const int* __restrict__ perm, const int* __restrict__ tileE,
    const int* __restrict__ tileRB, const int* __restrict__ tileRows,
    const int* __restrict__ ntiles, float* __restrict__ out)
{
  int rt = blockIdx.x;
  if (rt >= *ntiles) return;
  const int e       = tileE[rt];
  const int rowbase = tileRB[rt];
  const int nrows   = tileRows[rt];
  const int col0    = blockIdx.y * BN;

  __shared__ unsigned short As[BM][BK];
  __shared__ unsigned short Bs[BN][BK];
  __shared__ int   aRowS[BM];
  __shared__ float gateS[BM];

  const int tid = threadIdx.x;
  if (tid < BM) {
    int p = rowbase + tid;
    int tok = perm[p < (N_TOK - 1) ? p : (N_TOK - 1)];
    aRowS[tid] = tok;
    gateS[tid] = gate[tok];
  }
  __syncthreads();

  const float* wBase = ew + (size_t)e * DIM * DIM;
  const int lane = tid & 63;
  const int wid  = tid >> 6;
  const int wm   = (wid >> 1) * 64;
  const int wn   = (wid & 1) * 64;

  f32x4 acc[4][4] = {};
  char* AsB = (char*)&As[0][0];
  char* BsB = (char*)&Bs[0][0];

  for (int kt = 0; kt < DIM; kt += BK) {
#pragma unroll
    for (int i = 0; i < 4; i++) {
      int c   = tid + 256 * i;
      int row = c >> 3;
      int kc  = c & 7;
      {
        const float* src = x + (size_t)aRowS[row] * DIM + kt + kc * 8;
        float4 f0 = *reinterpret_cast<const float4*>(src);
        float4 f1 = *reinterpret_cast<const float4*>(src + 4);
        u32x4 pk;
        pk[0] = pack_bf2(f0.x, f0.y); pk[1] = pack_bf2(f0.z, f0.w);
        pk[2] = pack_bf2(f1.x, f1.y); pk[3] = pack_bf2(f1.z, f1.w);
        int off = row * (BK * 2) + ((kc * 16) ^ ((row & 7) << 4));
        *reinterpret_cast<u32x4*>(AsB + off) = pk;
      }
      {
        const float* src = wBase + (size_t)(col0 + row) * DIM + kt + kc * 8;
        float4 f0 = *reinterpret_cast<const float4*>(src);
        float4 f1 = *reinterpret_cast<const float4*>(src + 4);
        u32x4 pk;
        pk[0] = pack_bf2(f0.x, f0.y); pk[1] = pack_bf2(f0.z, f0.w);
        pk[2] = pack_bf2(f1.x, f1.y); pk[3] = pack_bf2(f1.z, f1.w);
        int off = row * (BK * 2) + ((kc * 16) ^ ((row & 7) << 4));
        *reinterpret_cast<u32x4*>(BsB + off) = pk;
      }
    }
    __syncthreads();

#pragma unroll
    for (int kk = 0; kk < 2; kk++) {
      int kbyte = kk * 64 + ((lane >> 4) * 16);
      short8 af[4], bfr[4];
#pragma unroll
      for (int m = 0; m < 4; m++) {
        int row = wm + m * 16 + (lane & 15);
        int off = row * (BK * 2) + (kbyte ^ ((row & 7) << 4));
        af[m] = *reinterpret_cast<const short8*>(AsB + off);
      }
#pragma unroll
      for (int n = 0; n < 4; n++) {
        int row = wn + n * 16 + (lane & 15);
        int off = row * (BK * 2) + (kbyte ^ ((row & 7) << 4));
        bfr[n] = *reinterpret_cast<const short8*>(BsB + off);
      }
#pragma unroll
      for (int m = 0; m < 4; m++)
#pragma unroll
        for (int n = 0; n < 4; n++)
          acc[m][n] = __builtin_amdgcn_mfma_f32_16x16x32_bf16(af[m], bfr[n], acc[m][n], 0, 0, 0);
    }
    __syncthreads();
  }

  const int cbase = col0 + wn;
  float bias[4];
#pragma unroll
  for (int n = 0; n < 4; n++)
    bias[n] = eb[(size_t)e * DIM + cbase + n * 16 + (lane & 15)];

#pragma unroll
  for (int m = 0; m < 4; m++) {
#pragma unroll
    for (int rg = 0; rg < 4; rg++) {
      int r = wm + m * 16 + ((lane >> 4) << 2) + rg;
      if (r < nrows) {
        int tok = aRowS[r];
        float g = gateS[r];
        float* orow = out + (size_t)tok * DIM + cbase;
#pragma unroll
        for (int n = 0; n < 4; n++)
          orow[n * 16 + (lane & 15)] = (acc[m][n][rg] + bias[n]) * g;
      }
    }
  }
}

extern "C" void kernel_launch(void* const* d_in, const int* in_sizes, int n_in,
                              void* d_out, int out_size, void* d_ws, size_t ws_size,
                              hipStream_t stream)
{
  const float* x  = (const float*)d_in[0];
  const float* ew = (const float*)d_in[1];
  const float* eb = (const float*)d_in[2];
  const float* rw = (const float*)d_in[3];
  const float* rb = (const float*)d_in[4];
  float* out = (float*)d_out;

  char* ws = (char*)d_ws;
  int*   eid      = (int*)(ws);                  // 8192 ints
  float* gate     = (float*)(ws + 32 * 1024);    // 8192 floats
  int*   counts   = (int*)(ws + 64 * 1024);
  int*   fill     = counts + 16;
  int*   basep    = counts + 32;
  int*   tileE    = counts + 48;                 // 128 slots
  int*   tileRB   = tileE + 128;
  int*   tileRows = tileE + 256;
  int*   ntiles   = tileE + 384;
  int*   perm     = (int*)(ws + 128 * 1024);     // 8192 ints
  unsigned short* xbuf = (unsigned short*)(ws + 192 * 1024);               // 32 MB
  unsigned short* wbuf = (unsigned short*)(ws + 192 * 1024 + ((size_t)N_TOK * DIM * 2)); // 64 MB

  const size_t WS_NEED = 192 * 1024 + (size_t)N_TOK * DIM * 2 + (size_t)NEXP * DIM * DIM * 2;
  const bool fast = (ws_size >= WS_NEED);

  init_kernel<<<1, 64, 0, stream>>>(counts, out);
  router_kernel<<<N_TOK / 4, 256, 0, stream>>>(x, rw, rb, eid, gate, counts,
                                               fast ? xbuf : (unsigned short*)nullptr);
  scan_kernel<<<1, 64, 0, stream>>>(counts, basep, tileE, tileRB, tileRows, ntiles);
  permute_kernel<<<N_TOK / 256, 256, 0, stream>>>(eid, basep, fill, perm);

  dim3 grid(MAXT, DIM / BN);
  if (fast) {
    convw_kernel<<<4096, 256, 0, stream>>>(ew, wbuf);
    moe_gemm<<<grid, 256, 0, stream>>>(xbuf, wbuf, eb, gate, perm, tileE, tileRB,
                                       tileRows, ntiles, out);
  } else {
    moe_gemm_fb<<<grid, 256, 0, stream>>>(x, ew, eb, gate, perm, tileE, tileRB,
                                          tileRows, ntiles, out);
  }
}

// Round 3
// 307.796 us; speedup vs baseline: 1.5815x; 1.2309x over previous
//
#include <hip/hip_runtime.h>
#include <hip/hip_bf16.h>

#define N_TOK 8192
#define DIM   2048
#define NEXP  8
#define BM    288          // 18 x 16; Σ ceil(c_e/288) ≈ 32 -> one block/CU
#define BN    256
#define BK    64
#define NT    (DIM / BK)   // 32 K-tiles
#define GRIDX 36           // worst-case row tiles: floor(8192/288)+7 <= 36

#define A_BUF_BYTES (BM * BK * 2)                       // 36864
#define B_BUF_BYTES (BN * BK * 2)                       // 32768
#define B_BASE      (2 * A_BUF_BYTES)                   // 73728
#define DYN_LDS     (2 * A_BUF_BYTES + 2 * B_BUF_BYTES) // 139264

typedef __attribute__((ext_vector_type(8))) short  short8;
typedef __attribute__((ext_vector_type(4))) float  f32x4;
typedef __attribute__((ext_vector_type(4))) unsigned int u32x4;

static __device__ __forceinline__ unsigned int pack_bf2(float a, float b) {
  union { __hip_bfloat16 h; unsigned short u; } ca, cb;
  ca.h = __float2bfloat16(a);
  cb.h = __float2bfloat16(b);
  return ((unsigned int)cb.u << 16) | (unsigned int)ca.u;
}

static __device__ __forceinline__ void gload16(const unsigned short* g, void* l) {
  __builtin_amdgcn_global_load_lds(
      (const __attribute__((address_space(1))) unsigned int*)(const void*)g,
      (__attribute__((address_space(3))) unsigned int*)l, 16, 0, 0);
}

// ---------------- prep: W -> bf16 convert + zero counters + loss=0 ----------------
__global__ __launch_bounds__(256) void prep_kernel(
    const float* __restrict__ w, unsigned short* __restrict__ wbuf,
    int* __restrict__ scratch, float* __restrict__ out)
{
  if (blockIdx.x == 0) {
    int t = threadIdx.x;
    if (t < 48) scratch[t] = 0;                    // counts[0..7]@0, fill@16
    if (t == 63) out[(size_t)N_TOK * DIM] = 0.0f;  // loss output
  }
  size_t idx    = (size_t)blockIdx.x * 256 + threadIdx.x;   // chunk of 8 elems
  const size_t stride = (size_t)gridDim.x * 256;
  const size_t total  = (size_t)NEXP * DIM * DIM / 8;
  for (; idx < total; idx += stride) {
    const float4* s = reinterpret_cast<const float4*>(w + idx * 8);
    float4 f0 = s[0], f1 = s[1];
    u32x4 pk;
    pk[0] = pack_bf2(f0.x, f0.y); pk[1] = pack_bf2(f0.z, f0.w);
    pk[2] = pack_bf2(f1.x, f1.y); pk[3] = pack_bf2(f1.z, f1.w);
    *reinterpret_cast<u32x4*>(wbuf + idx * 8) = pk;
  }
}

// ---------------- router (+ fused x -> bf16 convert), fp64 logits for argmax fidelity ----
__global__ __launch_bounds__(256) void router_kernel(
    const float* __restrict__ x, const float* __restrict__ rw,
    const float* __restrict__ rb, int* __restrict__ eid,
    float* __restrict__ gate, int* __restrict__ counts,
    unsigned short* __restrict__ xb)
{
  int tok  = (int)((blockIdx.x * 256 + threadIdx.x) >> 6);
  int lane = threadIdx.x & 63;
  const float4* xr = reinterpret_cast<const float4*>(x + (size_t)tok * DIM);
  double s[NEXP];
#pragma unroll
  for (int e = 0; e < NEXP; e++) s[e] = 0.0;
#pragma unroll
  for (int it = 0; it < DIM / 256; it++) {
    int v = lane + it * 64;            // float4 index within row
    float4 xv = xr[v];
    uint2 pk = make_uint2(pack_bf2(xv.x, xv.y), pack_bf2(xv.z, xv.w));
    *reinterpret_cast<uint2*>(xb + (size_t)tok * DIM + v * 4) = pk;
#pragma unroll
    for (int e = 0; e < NEXP; e++) {
      float4 wv = reinterpret_cast<const float4*>(rw + (size_t)e * DIM)[v];
      s[e] = fma((double)xv.x, (double)wv.x, s[e]);
      s[e] = fma((double)xv.y, (double)wv.y, s[e]);
      s[e] = fma((double)xv.z, (double)wv.z, s[e]);
      s[e] = fma((double)xv.w, (double)wv.w, s[e]);
    }
  }
#pragma unroll
  for (int e = 0; e < NEXP; e++) {
    double v = s[e];
#pragma unroll
    for (int off = 32; off > 0; off >>= 1) v += __shfl_xor(v, off, 64);
    s[e] = v;
  }
  if (lane == 0) {
    double lg[NEXP];
    double lmax = -1e300; int best = 0;
#pragma unroll
    for (int e = 0; e < NEXP; e++) {
      lg[e] = s[e] + (double)rb[e];
      if (lg[e] > lmax) { lmax = lg[e]; best = e; }  // strict > == first-occurrence argmax
    }
    float den = 0.f;
#pragma unroll
    for (int e = 0; e < NEXP; e++) den += expf((float)(lg[e] - lmax));
    eid[tok]  = best;
    gate[tok] = 1.0f / den;            // top softmax prob
    atomicAdd(&counts[best], 1);
  }
}

// ---------------- permute: group tokens by expert (base via inline prefix) ----------
__global__ void permute_kernel(const int* __restrict__ eid, const int* __restrict__ counts,
                               int* __restrict__ fill, int* __restrict__ perm)
{
  int i = blockIdx.x * blockDim.x + threadIdx.x;
  int e = eid[i];
  int base = 0;
#pragma unroll
  for (int j = 0; j < NEXP; j++) base += (j < e) ? counts[j] : 0;
  int pos = base + atomicAdd(&fill[e], 1);
  perm[pos] = i;
}

// ---------------- grouped GEMM: 288x256 tile, BK=64, 8 waves, 4-phase pipelined ------
// out[tok] = (x[tok] @ W[e]^T + b[e]) * gate[tok]
__global__ __launch_bounds__(512, 2) void moe_gemm(
    const unsigned short* __restrict__ xb, const unsigned short* __restrict__ wb,
    const float* __restrict__ eb, const float* __restrict__ gate,
    const int* __restrict__ perm, const int* __restrict__ counts,
    float* __restrict__ out)
{
  extern __shared__ char smem[];     // [0,72K) A dbuf; [72K,136K) B dbuf
  __shared__ int   aRowS[BM];
  __shared__ float gateS[BM];

  // bijective XCD-aware swizzle (grid 288 = 36*8, 288 % 8 == 0)
  int orig = blockIdx.x;
  int swz  = (orig & 7) * (GRIDX * 8 / 8) + (orig >> 3);
  int bx = swz >> 3;   // row-tile
  int by = swz & 7;    // col-tile

  // tile table from counts (redundant per-thread scalar work, ~50 instr)
  int cnt[NEXP];
#pragma unroll
  for (int j = 0; j < NEXP; j++) cnt[j] = counts[j];
  int e = 0, rowbase = 0, nrows = 0, found = 0;
  {
    int tsum = 0, bsum = 0;
#pragma unroll
    for (int j = 0; j < NEXP; j++) {
      int te = (cnt[j] + BM - 1) / BM;
      if (!found && bx < tsum + te) {
        int loc = bx - tsum;
        e = j;
        rowbase = bsum + loc * BM;
        int rem = cnt[j] - loc * BM;
        nrows = rem < BM ? rem : BM;
        found = 1;
      }
      tsum += te; bsum += cnt[j];
    }
    if (!found) return;
  }

  const int tid = threadIdx.x;
  if (tid < BM) {
    int idx = tid < nrows ? tid : (nrows - 1);
    int tok = perm[rowbase + idx];
    aRowS[tid] = tok;
    gateS[tid] = gate[tok];
  }
  __syncthreads();

  const int lane = tid & 63, wid = tid >> 6;
  const int lrow = lane >> 3;
  const int cblk = (lane & 7) ^ lrow;   // pre-swizzled source (XOR involution, rule #21)

  // --- staging assignment: A 288 rows = 36 wave-loads (waves 0-3: 5, waves 4-7: 4);
  //     B 256 rows = 32 wave-loads (4 each). dest = linear LDS, src column pre-swizzled.
  const unsigned short* wB = wb + (size_t)e * DIM * DIM;
  const unsigned short* aSrc[5];
  const unsigned short* bSrc[4];
  int aDst[5], bDst[4];
#pragma unroll
  for (int i = 0; i < 5; i++) {
    int r0 = (wid < 4) ? (wid * 40 + i * 8) : (160 + (wid - 4) * 32 + ((i < 4) ? i : 0) * 8);
    aSrc[i] = xb + (size_t)aRowS[r0 + lrow] * DIM + cblk * 8;
    aDst[i] = r0 * 128;
  }
#pragma unroll
  for (int i = 0; i < 4; i++) {
    int r0 = wid * 32 + i * 8;
    bSrc[i] = wB + (size_t)(by * BN + r0 + lrow) * DIM + cblk * 8;
    bDst[i] = B_BASE + r0 * 128;
  }

  // --- MFMA fragment addressing (waves 2M x 4N; per-wave 144x64 output) ---
  const int l15 = lane & 15;
  const int wr = wid >> 2, wc = wid & 3;
  const int aBase = (wr * 144 + l15) * 128;
  const int bBase = (wc * 64 + l15) * 128;
  const int x0 = ((lane >> 4) * 16) ^ ((lane & 7) << 4);
  const int x1 = (64 + (lane >> 4) * 16) ^ ((lane & 7) << 4);

  // --- prologue: stage tile 0 into buffer 0 ---
#pragma unroll
  for (int i = 0; i < 4; i++) gload16(bSrc[i], smem + bDst[i]);
#pragma unroll
  for (int i = 0; i < 5; i++)
    if (i < 4 || wid < 4) gload16(aSrc[i], smem + aDst[i]);
#pragma unroll
  for (int i = 0; i < 4; i++) bSrc[i] += BK;
#pragma unroll
  for (int i = 0; i < 5; i++) aSrc[i] += BK;
  asm volatile("s_waitcnt vmcnt(0)" ::: "memory");
  __builtin_amdgcn_s_barrier();

  f32x4 acc[9][4] = {};

  for (int t = 0; t < NT; t++) {
    const char* Ac = smem + (t & 1) * A_BUF_BYTES;
    const char* Bc = smem + B_BASE + (t & 1) * B_BUF_BYTES;
    const int   np = (t + 1) & 1;
    const bool  pf = (t + 1 < NT);

    short8 af[5], bf[4];

    // ---- phase 0: kk0, m0-4 ∥ issue B(t+1) ----
#pragma unroll
    for (int n = 0; n < 4; n++) bf[n] = *(const short8*)(Bc + bBase + n * 2048 + x0);
#pragma unroll
    for (int m = 0; m < 5; m++) af[m] = *(const short8*)(Ac + aBase + m * 2048 + x0);
    if (pf) {
#pragma unroll
      for (int i = 0; i < 4; i++) gload16(bSrc[i], smem + np * B_BUF_BYTES + bDst[i]);
    }
    __builtin_amdgcn_s_barrier();
    __builtin_amdgcn_s_setprio(1);
#pragma unroll
    for (int m = 0; m < 5; m++)
#pragma unroll
      for (int n = 0; n < 4; n++)
        acc[m][n] = __builtin_amdgcn_mfma_f32_16x16x32_bf16(af[m], bf[n], acc[m][n], 0, 0, 0);
    __builtin_amdgcn_s_setprio(0);
    __builtin_amdgcn_s_barrier();

    // ---- phase 1: kk0, m5-8 ∥ issue A(t+1) ----
#pragma unroll
    for (int m = 0; m < 4; m++) af[m] = *(const short8*)(Ac + aBase + (m + 5) * 2048 + x0);
    if (pf) {
#pragma unroll
      for (int i = 0; i < 5; i++)
        if (i < 4 || wid < 4) gload16(aSrc[i], smem + np * A_BUF_BYTES + aDst[i]);
#pragma unroll
      for (int i = 0; i < 4; i++) bSrc[i] += BK;
#pragma unroll
      for (int i = 0; i < 5; i++) aSrc[i] += BK;
    }
    __builtin_amdgcn_s_barrier();
    __builtin_amdgcn_s_setprio(1);
#pragma unroll
    for (int m = 0; m < 4; m++)
#pragma unroll
      for (int n = 0; n < 4; n++)
        acc[m + 5][n] = __builtin_amdgcn_mfma_f32_16x16x32_bf16(af[m], bf[n], acc[m + 5][n], 0, 0, 0);
    __builtin_amdgcn_s_setprio(0);
    __builtin_amdgcn_s_barrier();

    // ---- phase 2: kk1, m0-4 ----
#pragma unroll
    for (int n = 0; n < 4; n++) bf[n] = *(const short8*)(Bc + bBase + n * 2048 + x1);
#pragma unroll
    for (int m = 0; m < 5; m++) af[m] = *(const short8*)(Ac + aBase + m * 2048 + x1);
    __builtin_amdgcn_s_barrier();
    __builtin_amdgcn_s_setprio(1);
#pragma unroll
    for (int m = 0; m < 5; m++)
#pragma unroll
      for (int n = 0; n < 4; n++)
        acc[m][n] = __builtin_amdgcn_mfma_f32_16x16x32_bf16(af[m], bf[n], acc[m][n], 0, 0, 0);
    __builtin_amdgcn_s_setprio(0);
    __builtin_amdgcn_s_barrier();

    // ---- phase 3: kk1, m5-8; drain prefetch (issued 2-3 phases ago => ~free) ----
#pragma unroll
    for (int m = 0; m < 4; m++) af[m] = *(const short8*)(Ac + aBase + (m + 5) * 2048 + x1);
    asm volatile("s_waitcnt vmcnt(0)" ::: "memory");
    __builtin_amdgcn_s_barrier();
    __builtin_amdgcn_s_setprio(1);
#pragma unroll
    for (int m = 0; m < 4; m++)
#pragma unroll
      for (int n = 0; n < 4; n++)
        acc[m + 5][n] = __builtin_amdgcn_mfma_f32_16x16x32_bf16(af[m], bf[n], acc[m + 5][n], 0, 0, 0);
    __builtin_amdgcn_s_setprio(0);
    __builtin_amdgcn_s_barrier();
  }

  // ---- epilogue: +bias, *gate, scatter by token ----
  const int cb = by * BN + wc * 64;
  const float* ebE = eb + (size_t)e * DIM;
  float bias[4];
#pragma unroll
  for (int n = 0; n < 4; n++) bias[n] = ebE[cb + n * 16 + l15];
  const int rsub = (lane >> 4) * 4;
#pragma unroll
  for (int m = 0; m < 9; m++) {
    int r0 = wr * 144 + m * 16 + rsub;
#pragma unroll
    for (int rg = 0; rg < 4; rg++) {
      int r = r0 + rg;
      if (r < nrows) {
        float g = gateS[r];
        float* orow = out + (size_t)aRowS[r] * DIM + cb;
#pragma unroll
        for (int n = 0; n < 4; n++)
          orow[n * 16 + l15] = (acc[m][n][rg] + bias[n]) * g;
      }
    }
  }
}

extern "C" void kernel_launch(void* const* d_in, const int* in_sizes, int n_in,
                              void* d_out, int out_size, void* d_ws, size_t ws_size,
                              hipStream_t stream)
{
  const float* x  = (const float*)d_in[0];
  const float* ew = (const float*)d_in[1];
  const float* eb = (const float*)d_in[2];
  const float* rw = (const float*)d_in[3];
  const float* rb = (const float*)d_in[4];
  float* out = (float*)d_out;

  char* ws = (char*)d_ws;
  int*   eid    = (int*)(ws);                  // 8192 ints
  float* gate   = (float*)(ws + 32 * 1024);    // 8192 floats
  int*   counts = (int*)(ws + 64 * 1024);      // [0..7]
  int*   fill   = counts + 16;
  int*   perm   = (int*)(ws + 128 * 1024);     // 8192 ints
  unsigned short* xbuf = (unsigned short*)(ws + 192 * 1024);                               // 32 MB
  unsigned short* wbuf = (unsigned short*)(ws + 192 * 1024 + ((size_t)N_TOK * DIM * 2));   // 64 MB

  hipFuncSetAttribute(reinterpret_cast<const void*>(moe_gemm),
                      hipFuncAttributeMaxDynamicSharedMemorySize, DYN_LDS);

  prep_kernel<<<4096, 256, 0, stream>>>(ew, wbuf, counts, out);
  router_kernel<<<N_TOK / 4, 256, 0, stream>>>(x, rw, rb, eid, gate, counts, xbuf);
  permute_kernel<<<N_TOK / 256, 256, 0, stream>>>(eid, counts, fill, perm);
  moe_gemm<<<dim3(GRIDX * 8), 512, DYN_LDS, stream>>>(xbuf, wbuf, eb, gate, perm,
                                                      counts, out);
}

// Round 4
// 246.723 us; speedup vs baseline: 1.9729x; 1.2475x over previous
//
#include <hip/hip_runtime.h>
#include <hip/hip_bf16.h>

#define N_TOK 8192
#define DIM   2048
#define NEXP  8
#define BM    288          // 18 x 16; sum ceil(c_e/288) == 32 for c in [865,1152]
#define BN    256
#define BK    64
#define NT    (DIM / BK)   // 32 K-tiles
#define NBLK  256          // persistent: exactly 1 block per CU

#define A_BUF_BYTES (BM * BK * 2)                       // 36864
#define B_BUF_BYTES (BN * BK * 2)                       // 32768
#define B_BASE      (2 * A_BUF_BYTES)                   // 73728
#define DYN_LDS     (2 * A_BUF_BYTES + 2 * B_BUF_BYTES) // 139264

typedef __attribute__((ext_vector_type(8))) short  short8;
typedef __attribute__((ext_vector_type(4))) float  f32x4;
typedef __attribute__((ext_vector_type(4))) unsigned int u32x4;

static __device__ __forceinline__ unsigned int pack_bf2(float a, float b) {
  union { __hip_bfloat16 h; unsigned short u; } ca, cb;
  ca.h = __float2bfloat16(a);
  cb.h = __float2bfloat16(b);
  return ((unsigned int)cb.u << 16) | (unsigned int)ca.u;
}

static __device__ __forceinline__ void gload16(const unsigned short* g, void* l) {
  __builtin_amdgcn_global_load_lds(
      (const __attribute__((address_space(1))) unsigned int*)(const void*)g,
      (__attribute__((address_space(3))) unsigned int*)l, 16, 0, 0);
}

// ------- fused prep (W->bf16) + router (+x->bf16), block-range split -------
// blocks [0,2048): router, 4 tokens each (1 wave/token), fp64 logits
// blocks [2048,4096): W convert, grid-stride
__global__ __launch_bounds__(256) void fused_prep_router(
    const float* __restrict__ x, const float* __restrict__ rw,
    const float* __restrict__ rb, const float* __restrict__ w,
    unsigned short* __restrict__ wbuf, int* __restrict__ eid,
    float* __restrict__ gate, int* __restrict__ counts,
    unsigned short* __restrict__ xb)
{
  if (blockIdx.x >= 2048) {
    // ---- W convert: 8 iterations of 16B-in/8B-out per thread ----
    size_t idx    = (size_t)(blockIdx.x - 2048) * 256 + threadIdx.x;  // chunk of 8 elems
    const size_t stride = 2048 * 256;
    const size_t total  = (size_t)NEXP * DIM * DIM / 8;
    for (; idx < total; idx += stride) {
      const float4* s = reinterpret_cast<const float4*>(w + idx * 8);
      float4 f0 = s[0], f1 = s[1];
      u32x4 pk;
      pk[0] = pack_bf2(f0.x, f0.y); pk[1] = pack_bf2(f0.z, f0.w);
      pk[2] = pack_bf2(f1.x, f1.y); pk[3] = pack_bf2(f1.z, f1.w);
      *reinterpret_cast<u32x4*>(wbuf + idx * 8) = pk;
    }
    return;
  }
  // ---- router ----
  int tok  = (int)((blockIdx.x * 256 + threadIdx.x) >> 6);
  int lane = threadIdx.x & 63;
  const float4* xr = reinterpret_cast<const float4*>(x + (size_t)tok * DIM);
  double s[NEXP];
#pragma unroll
  for (int e = 0; e < NEXP; e++) s[e] = 0.0;
#pragma unroll
  for (int it = 0; it < DIM / 256; it++) {
    int v = lane + it * 64;            // float4 index within row
    float4 xv = xr[v];
    uint2 pk = make_uint2(pack_bf2(xv.x, xv.y), pack_bf2(xv.z, xv.w));
    *reinterpret_cast<uint2*>(xb + (size_t)tok * DIM + v * 4) = pk;
#pragma unroll
    for (int e = 0; e < NEXP; e++) {
      float4 wv = reinterpret_cast<const float4*>(rw + (size_t)e * DIM)[v];
      s[e] = fma((double)xv.x, (double)wv.x, s[e]);
      s[e] = fma((double)xv.y, (double)wv.y, s[e]);
      s[e] = fma((double)xv.z, (double)wv.z, s[e]);
      s[e] = fma((double)xv.w, (double)wv.w, s[e]);
    }
  }
#pragma unroll
  for (int e = 0; e < NEXP; e++) {
    double v = s[e];
#pragma unroll
    for (int off = 32; off > 0; off >>= 1) v += __shfl_xor(v, off, 64);
    s[e] = v;
  }
  if (lane == 0) {
    double lg[NEXP];
    double lmax = -1e300; int best = 0;
#pragma unroll
    for (int e = 0; e < NEXP; e++) {
      lg[e] = s[e] + (double)rb[e];
      if (lg[e] > lmax) { lmax = lg[e]; best = e; }  // strict > == first-occurrence argmax
    }
    float den = 0.f;
#pragma unroll
    for (int e = 0; e < NEXP; e++) den += expf((float)(lg[e] - lmax));
    eid[tok]  = best;
    gate[tok] = 1.0f / den;            // top softmax prob
    atomicAdd(&counts[best], 1);
  }
}

// ---------------- permute: group tokens by expert ----------------
__global__ void permute_kernel(const int* __restrict__ eid, const int* __restrict__ counts,
                               int* __restrict__ fill, int* __restrict__ perm)
{
  int i = blockIdx.x * blockDim.x + threadIdx.x;
  int e = eid[i];
  int base = 0;
#pragma unroll
  for (int j = 0; j < NEXP; j++) base += (j < e) ? counts[j] : 0;
  int pos = base + atomicAdd(&fill[e], 1);
  perm[pos] = i;
}

// ------- grouped GEMM: 288x256 tile, BK=64, 8 waves, 4-phase, persistent 256 blocks ---
// out[tok] = (x[tok] @ W[e]^T + b[e]) * gate[tok]
__global__ __launch_bounds__(512, 2) void moe_gemm(
    const unsigned short* __restrict__ xb, const unsigned short* __restrict__ wb,
    const float* __restrict__ eb, const float* __restrict__ gate,
    const int* __restrict__ perm, const int* __restrict__ counts,
    float* __restrict__ out)
{
  extern __shared__ char smem[];     // [0,72K) A dbuf; [72K,136K) B dbuf
  __shared__ int   aRowS[BM];
  __shared__ float gateS[BM];

  const int tid  = threadIdx.x;
  const int lane = tid & 63, wid = tid >> 6;

  int cnt[NEXP];
#pragma unroll
  for (int j = 0; j < NEXP; j++) cnt[j] = counts[j];
  int ttot = 0;
#pragma unroll
  for (int j = 0; j < NEXP; j++) ttot += (cnt[j] + BM - 1) / BM;
  ttot *= 8;

  // tile-invariant addressing
  const int lrow = lane >> 3;
  const int cblk = (lane & 7) ^ lrow;   // pre-swizzled source col (XOR involution, rule #21)
  int aDst[5], bDst[4], aR0[5], bR0[4];
#pragma unroll
  for (int i = 0; i < 5; i++) {
    int r0 = (wid < 4) ? (wid * 40 + i * 8) : (160 + (wid - 4) * 32 + ((i < 4) ? i : 0) * 8);
    aR0[i]  = r0;
    aDst[i] = r0 * 128;
  }
#pragma unroll
  for (int i = 0; i < 4; i++) {
    int r0 = wid * 32 + i * 8;
    bR0[i]  = r0;
    bDst[i] = B_BASE + r0 * 128;
  }
  const int l15 = lane & 15;
  const int wr = wid >> 2, wc = wid & 3;
  const int aBase = (wr * 144 + l15) * 128;
  const int bBase = (wc * 64 + l15) * 128;
  const int x0 = ((lane >> 4) * 16) ^ ((lane & 7) << 4);
  const int x1 = (64 + (lane >> 4) * 16) ^ ((lane & 7) << 4);
  const int rsub = (lane >> 4) * 4;

  for (int tt = blockIdx.x; tt < ttot; tt += NBLK) {
    const int bx = tt >> 3, by = tt & 7;

    int e = 0, rowbase = 0, nrows = 0, found = 0;
    {
      int tsum = 0, bsum = 0;
#pragma unroll
      for (int j = 0; j < NEXP; j++) {
        int te = (cnt[j] + BM - 1) / BM;
        if (!found && bx < tsum + te) {
          int loc = bx - tsum;
          e = j;
          rowbase = bsum + loc * BM;
          int rem = cnt[j] - loc * BM;
          nrows = rem < BM ? rem : BM;
          found = 1;
        }
        tsum += te; bsum += cnt[j];
      }
    }

    __syncthreads();   // previous tile's epilogue readers done before overwrite
    if (tid < BM) {
      int idx = tid < nrows ? tid : (nrows - 1);
      int tok = perm[rowbase + idx];
      aRowS[tid] = tok;
      gateS[tid] = gate[tok];
    }
    __syncthreads();

    const unsigned short* wB = wb + (size_t)e * DIM * DIM;
    const unsigned short* aSrc[5];
    const unsigned short* bSrc[4];
#pragma unroll
    for (int i = 0; i < 5; i++)
      aSrc[i] = xb + (size_t)aRowS[aR0[i] + lrow] * DIM + cblk * 8;
#pragma unroll
    for (int i = 0; i < 4; i++)
      bSrc[i] = wB + (size_t)(by * BN + bR0[i] + lrow) * DIM + cblk * 8;

    // --- prologue: stage K-tile 0 into buffer 0 ---
#pragma unroll
    for (int i = 0; i < 4; i++) gload16(bSrc[i], smem + bDst[i]);
#pragma unroll
    for (int i = 0; i < 5; i++)
      if (i < 4 || wid < 4) gload16(aSrc[i], smem + aDst[i]);
#pragma unroll
    for (int i = 0; i < 4; i++) bSrc[i] += BK;
#pragma unroll
    for (int i = 0; i < 5; i++) aSrc[i] += BK;
    asm volatile("s_waitcnt vmcnt(0)" ::: "memory");
    __builtin_amdgcn_s_barrier();

    f32x4 acc[9][4] = {};

    for (int t = 0; t < NT; t++) {
      const char* Ac = smem + (t & 1) * A_BUF_BYTES;
      const char* Bc = smem + B_BASE + (t & 1) * B_BUF_BYTES;
      const int   np = (t + 1) & 1;
      const bool  pf = (t + 1 < NT);

      short8 af[5], bf[4];

      // ---- phase 0: kk0, m0-4 ; issue B(t+1) ----
#pragma unroll
      for (int n = 0; n < 4; n++) bf[n] = *(const short8*)(Bc + bBase + n * 2048 + x0);
#pragma unroll
      for (int m = 0; m < 5; m++) af[m] = *(const short8*)(Ac + aBase + m * 2048 + x0);
      if (pf) {
#pragma unroll
        for (int i = 0; i < 4; i++) gload16(bSrc[i], smem + np * B_BUF_BYTES + bDst[i]);
      }
      __builtin_amdgcn_s_barrier();
      __builtin_amdgcn_s_setprio(1);
#pragma unroll
      for (int m = 0; m < 5; m++)
#pragma unroll
        for (int n = 0; n < 4; n++)
          acc[m][n] = __builtin_amdgcn_mfma_f32_16x16x32_bf16(af[m], bf[n], acc[m][n], 0, 0, 0);
      __builtin_amdgcn_s_setprio(0);
      __builtin_amdgcn_s_barrier();

      // ---- phase 1: kk0, m5-8 ; issue A(t+1) ----
#pragma unroll
      for (int m = 0; m < 4; m++) af[m] = *(const short8*)(Ac + aBase + (m + 5) * 2048 + x0);
      if (pf) {
#pragma unroll
        for (int i = 0; i < 5; i++)
          if (i < 4 || wid < 4) gload16(aSrc[i], smem + np * A_BUF_BYTES + aDst[i]);
#pragma unroll
        for (int i = 0; i < 4; i++) bSrc[i] += BK;
#pragma unroll
        for (int i = 0; i < 5; i++) aSrc[i] += BK;
      }
      __builtin_amdgcn_s_barrier();
      __builtin_amdgcn_s_setprio(1);
#pragma unroll
      for (int m = 0; m < 4; m++)
#pragma unroll
        for (int n = 0; n < 4; n++)
          acc[m + 5][n] = __builtin_amdgcn_mfma_f32_16x16x32_bf16(af[m], bf[n], acc[m + 5][n], 0, 0, 0);
      __builtin_amdgcn_s_setprio(0);
      __builtin_amdgcn_s_barrier();

      // ---- phase 2: kk1, m0-4 ----
#pragma unroll
      for (int n = 0; n < 4; n++) bf[n] = *(const short8*)(Bc + bBase + n * 2048 + x1);
#pragma unroll
      for (int m = 0; m < 5; m++) af[m] = *(const short8*)(Ac + aBase + m * 2048 + x1);
      __builtin_amdgcn_s_barrier();
      __builtin_amdgcn_s_setprio(1);
#pragma unroll
      for (int m = 0; m < 5; m++)
#pragma unroll
        for (int n = 0; n < 4; n++)
          acc[m][n] = __builtin_amdgcn_mfma_f32_16x16x32_bf16(af[m], bf[n], acc[m][n], 0, 0, 0);
      __builtin_amdgcn_s_setprio(0);
      __builtin_amdgcn_s_barrier();

      // ---- phase 3: kk1, m5-8 ; drain AFTER MFMA (max latency cover) ----
#pragma unroll
      for (int m = 0; m < 4; m++) af[m] = *(const short8*)(Ac + aBase + (m + 5) * 2048 + x1);
      __builtin_amdgcn_s_barrier();
      __builtin_amdgcn_s_setprio(1);
#pragma unroll
      for (int m = 0; m < 4; m++)
#pragma unroll
        for (int n = 0; n < 4; n++)
          acc[m + 5][n] = __builtin_amdgcn_mfma_f32_16x16x32_bf16(af[m], bf[n], acc[m + 5][n], 0, 0, 0);
      __builtin_amdgcn_s_setprio(0);
      asm volatile("s_waitcnt vmcnt(0)" ::: "memory");
      __builtin_amdgcn_s_barrier();
    }

    // ---- epilogue: +bias, *gate, scatter by token ----
    const int cb = by * BN + wc * 64;
    const float* ebE = eb + (size_t)e * DIM;
    float bias[4];
#pragma unroll
    for (int n = 0; n < 4; n++) bias[n] = ebE[cb + n * 16 + l15];
#pragma unroll
    for (int m = 0; m < 9; m++) {
      int r0 = wr * 144 + m * 16 + rsub;
#pragma unroll
      for (int rg = 0; rg < 4; rg++) {
        int r = r0 + rg;
        if (r < nrows) {
          float g = gateS[r];
          float* orow = out + (size_t)aRowS[r] * DIM + cb;
#pragma unroll
          for (int n = 0; n < 4; n++)
            orow[n * 16 + l15] = (acc[m][n][rg] + bias[n]) * g;
        }
      }
    }
  }
}

extern "C" void kernel_launch(void* const* d_in, const int* in_sizes, int n_in,
                              void* d_out, int out_size, void* d_ws, size_t ws_size,
                              hipStream_t stream)
{
  const float* x  = (const float*)d_in[0];
  const float* ew = (const float*)d_in[1];
  const float* eb = (const float*)d_in[2];
  const float* rw = (const float*)d_in[3];
  const float* rb = (const float*)d_in[4];
  float* out = (float*)d_out;

  char* ws = (char*)d_ws;
  int*   eid    = (int*)(ws);                  // 8192 ints
  float* gate   = (float*)(ws + 32 * 1024);    // 8192 floats
  int*   counts = (int*)(ws + 64 * 1024);      // [0..7]
  int*   fill   = counts + 16;
  int*   perm   = (int*)(ws + 128 * 1024);     // 8192 ints
  unsigned short* xbuf = (unsigned short*)(ws + 192 * 1024);                               // 32 MB
  unsigned short* wbuf = (unsigned short*)(ws + 192 * 1024 + ((size_t)N_TOK * DIM * 2));   // 64 MB

  hipFuncSetAttribute(reinterpret_cast<const void*>(moe_gemm),
                      hipFuncAttributeMaxDynamicSharedMemorySize, DYN_LDS);

  hipMemsetAsync(counts, 0, 192, stream);                                   // counts+fill
  hipMemsetAsync(out + (size_t)N_TOK * DIM, 0, sizeof(float), stream);      // loss = 0
  fused_prep_router<<<4096, 256, 0, stream>>>(x, rw, rb, ew, wbuf, eid, gate, counts, xbuf);
  permute_kernel<<<N_TOK / 256, 256, 0, stream>>>(eid, counts, fill, perm);
  moe_gemm<<<NBLK, 512, DYN_LDS, stream>>>(xbuf, wbuf, eb, gate, perm, counts, out);
}